// Round 14
// baseline (737.787 us; speedup 1.0000x reference)
//
#include <hip/hip_runtime.h>
#include <hip/hip_bf16.h>

#define HID 768
#define DW  200
#define NW  5

// ===========================================================================
// R12 post-mortem: ANY __launch_bounds__ min-waves hint makes the allocator
// chase occupancy and spill the ~100-reg live set (R11: 48 VGPR/55MB writes,
// R12: 64 VGPR/31MB). Unhinted builds (R9: 96 VGPR, R10: 76) had WRITE ==
// output exactly. R13: (1) no launch_bounds on fused; (2) proj merged into
// fused (P2 computed in-register via one more GEMM2-shaped k-loop) -- deletes
// a ~200us dispatch and the 50MB P2 HBM round-trip.
//   G = attn_W @ W2^T   (gw_kernel, ~20us)
//   fused (4 tokens/block, 2048 blocks, smem union 12KB):
//     loT stage -> p2v[4][3] = LO @ G (regs)
//     weT halves -> th[20][3] = tanh(WE@W1+b1) (regs)
//     scores = th.p2v (shuffle reduce); masked softmax (N=5)
//     athT (smem union) -> GEMM2 @ W2 -> +b2+LO -> LayerNorm
// ===========================================================================

__device__ __forceinline__ float fast_tanh(float x) {
    float ax = fabsf(x);
    float z  = __expf(-2.0f * ax);
    float r  = (1.0f - z) * __builtin_amdgcn_rcpf(1.0f + z);
    return copysignf(r, x);
}

// ---------------------------------------------------------------------------
// Kernel B: G[d,h] = sum_e attn_W[d,e] * W2[h,e]  (NT GEMM, 768^3, tiny).
// ---------------------------------------------------------------------------
__global__ __launch_bounds__(256)
void gw_kernel(const float* __restrict__ A,
               const float* __restrict__ W2,
               float* __restrict__ G)
{
    __shared__ __align__(16) float AsT[32][68];
    __shared__ __align__(16) float WsT[32][68];
    const int tid = threadIdx.x;
    const int bd = blockIdx.x / (HID / 64), bh = blockIdx.x % (HID / 64);
    const int d0 = bd * 64, h0 = bh * 64;
    const int tx = tid % 16, ty = tid / 16;

    float acc[4][4];
    #pragma unroll
    for (int i = 0; i < 4; ++i)
        #pragma unroll
        for (int j = 0; j < 4; ++j) acc[i][j] = 0.f;

    for (int e0 = 0; e0 < HID; e0 += 32) {
        __syncthreads();
        #pragma unroll
        for (int q = 0; q < 2; ++q) {
            int idx = q * 256 + tid;
            int r = idx / 8, c4 = idx % 8;
            float4 va = *reinterpret_cast<const float4*>(&A [(size_t)(d0 + r) * HID + e0 + c4 * 4]);
            AsT[c4 * 4 + 0][r] = va.x; AsT[c4 * 4 + 1][r] = va.y;
            AsT[c4 * 4 + 2][r] = va.z; AsT[c4 * 4 + 3][r] = va.w;
            float4 vw = *reinterpret_cast<const float4*>(&W2[(size_t)(h0 + r) * HID + e0 + c4 * 4]);
            WsT[c4 * 4 + 0][r] = vw.x; WsT[c4 * 4 + 1][r] = vw.y;
            WsT[c4 * 4 + 2][r] = vw.z; WsT[c4 * 4 + 3][r] = vw.w;
        }
        __syncthreads();
        #pragma unroll 4
        for (int e = 0; e < 32; ++e) {
            float4 a4 = *reinterpret_cast<const float4*>(&AsT[e][ty * 4]);
            float4 b4 = *reinterpret_cast<const float4*>(&WsT[e][tx * 4]);
            float av[4] = {a4.x, a4.y, a4.z, a4.w};
            float bv[4] = {b4.x, b4.y, b4.z, b4.w};
            #pragma unroll
            for (int i = 0; i < 4; ++i)
                #pragma unroll
                for (int j = 0; j < 4; ++j)
                    acc[i][j] = fmaf(av[i], bv[j], acc[i][j]);
        }
    }
    #pragma unroll
    for (int i = 0; i < 4; ++i) {
        float4 o = {acc[i][0], acc[i][1], acc[i][2], acc[i][3]};
        *reinterpret_cast<float4*>(&G[(size_t)(d0 + ty * 4 + i) * HID + h0 + tx * 4]) = o;
    }
}

// ---------------------------------------------------------------------------
// Kernel D (fused, proj merged): 4 tokens/block, 2048 blocks, no launch_bounds.
// ---------------------------------------------------------------------------
#define KSPLIT 100   // MLP1 k-halves; WE tile = [KSPLIT][20] = 8 KB

__global__
void fused_kernel(const float* __restrict__ WE,
                  const float* __restrict__ W1,
                  const float* __restrict__ b1,
                  const float* __restrict__ W2,
                  const float* __restrict__ b2,
                  const float* __restrict__ LO,
                  const float* __restrict__ G,
                  const int* __restrict__ mask,
                  const float* __restrict__ gamma,
                  const float* __restrict__ beta,
                  float* __restrict__ out)
{
    // union buffer (12.3 KB), barrier-separated phases:
    //   phase 0: loT  [HID][4]     (LO tile transposed, proj A-operand)
    //   phase 1: weT  [KSPLIT][20] (8 KB, staged twice)
    //   phase 2: athT [HID][4]
    __shared__ __align__(16) float smem[HID * 4];    // 12288 B
    __shared__ float red[4][32];
    __shared__ float sc_s[4][NW];
    __shared__ float at_s[4][NW];
    __shared__ float mus[4], rss[4];

    const int tid = threadIdx.x;
    const int wave = tid >> 6, lane = tid & 63;
    const long tok0 = (long)blockIdx.x * 4;
    const long row0 = tok0 * NW;         // 20 word-rows for this block

    // ---- phase 0: stage LO tile transposed: smem[k*4 + t] ----
    for (int i = tid; i < 4 * (HID / 4); i += 256) {
        int t = i / (HID / 4), k4 = i % (HID / 4);
        float4 v = *reinterpret_cast<const float4*>(&LO[(tok0 + t) * HID + k4 * 4]);
        smem[(k4 * 4 + 0) * 4 + t] = v.x;
        smem[(k4 * 4 + 1) * 4 + t] = v.y;
        smem[(k4 * 4 + 2) * 4 + t] = v.z;
        smem[(k4 * 4 + 3) * 4 + t] = v.w;
    }
    __syncthreads();

    // ---- proj: p2v[tt][c] = sum_k LO[t,k] * G[k, c*256+tid] ----
    float p2v[4][3];
    #pragma unroll
    for (int tt = 0; tt < 4; ++tt) { p2v[tt][0] = 0.f; p2v[tt][1] = 0.f; p2v[tt][2] = 0.f; }

    #pragma unroll 4
    for (int k = 0; k < HID; ++k) {
        float4 a4 = *reinterpret_cast<const float4*>(&smem[k * 4]);
        float g0 = G[(size_t)k * HID + tid];
        float g1 = G[(size_t)k * HID + 256 + tid];
        float g2 = G[(size_t)k * HID + 512 + tid];
        p2v[0][0] = fmaf(a4.x, g0, p2v[0][0]); p2v[0][1] = fmaf(a4.x, g1, p2v[0][1]); p2v[0][2] = fmaf(a4.x, g2, p2v[0][2]);
        p2v[1][0] = fmaf(a4.y, g0, p2v[1][0]); p2v[1][1] = fmaf(a4.y, g1, p2v[1][1]); p2v[1][2] = fmaf(a4.y, g2, p2v[1][2]);
        p2v[2][0] = fmaf(a4.z, g0, p2v[2][0]); p2v[2][1] = fmaf(a4.z, g1, p2v[2][1]); p2v[2][2] = fmaf(a4.z, g2, p2v[2][2]);
        p2v[3][0] = fmaf(a4.w, g0, p2v[3][0]); p2v[3][1] = fmaf(a4.w, g1, p2v[3][1]); p2v[3][2] = fmaf(a4.w, g2, p2v[3][2]);
    }

    // ---- MLP1 in 2 k-halves: th[r][c], j = c*256+tid ----
    float th[20][3];
    #pragma unroll
    for (int r = 0; r < 20; ++r) { th[r][0] = 0.f; th[r][1] = 0.f; th[r][2] = 0.f; }

    #pragma unroll 1
    for (int half = 0; half < 2; ++half) {
        const int kbase = half * KSPLIT;
        __syncthreads();   // previous phase done with smem
        for (int i = tid; i < 20 * (KSPLIT / 4); i += 256) {
            int r = i / (KSPLIT / 4), k4 = i % (KSPLIT / 4);
            float4 v = *reinterpret_cast<const float4*>(&WE[(row0 + r) * DW + kbase + k4 * 4]);
            smem[(k4 * 4 + 0) * 20 + r] = v.x;
            smem[(k4 * 4 + 1) * 20 + r] = v.y;
            smem[(k4 * 4 + 2) * 20 + r] = v.z;
            smem[(k4 * 4 + 3) * 20 + r] = v.w;
        }
        __syncthreads();

        #pragma unroll 2
        for (int kk = 0; kk < KSPLIT; ++kk) {
            int k = kbase + kk;
            float a[20];
            #pragma unroll
            for (int q = 0; q < 5; ++q) {
                float4 v = *reinterpret_cast<const float4*>(&smem[kk * 20 + q * 4]);
                a[q * 4 + 0] = v.x; a[q * 4 + 1] = v.y; a[q * 4 + 2] = v.z; a[q * 4 + 3] = v.w;
            }
            float w0 = W1[(size_t)k * HID + tid];
            float w1 = W1[(size_t)k * HID + 256 + tid];
            float w2 = W1[(size_t)k * HID + 512 + tid];
            #pragma unroll
            for (int r = 0; r < 20; ++r) {
                th[r][0] = fmaf(a[r], w0, th[r][0]);
                th[r][1] = fmaf(a[r], w1, th[r][1]);
                th[r][2] = fmaf(a[r], w2, th[r][2]);
            }
        }
    }
    {
        float bb0 = b1[tid], bb1 = b1[256 + tid], bb2 = b1[512 + tid];
        #pragma unroll
        for (int r = 0; r < 20; ++r) {
            th[r][0] = fast_tanh(th[r][0] + bb0);
            th[r][1] = fast_tanh(th[r][1] + bb1);
            th[r][2] = fast_tanh(th[r][2] + bb2);
        }
    }

    // ---- scores: s[tt][n] = sum_j th*p2v ; shuffle + cross-wave reduce ----
    #pragma unroll
    for (int tt = 0; tt < 4; ++tt)
        #pragma unroll
        for (int n = 0; n < NW; ++n) {
            int r = tt * NW + n;
            float s = th[r][0] * p2v[tt][0];
            s = fmaf(th[r][1], p2v[tt][1], s);
            s = fmaf(th[r][2], p2v[tt][2], s);
            #pragma unroll
            for (int off = 32; off; off >>= 1) s += __shfl_xor(s, off);
            if (lane == 0) red[wave][r] = s;
        }
    __syncthreads();
    if (tid < 20) {
        float s = red[0][tid] + red[1][tid] + red[2][tid] + red[3][tid];
        sc_s[tid / NW][tid % NW] = s;
    }
    __syncthreads();

    // ---- masked softmax over N=5 ----
    if (tid < 4) {
        float v[NW]; float m = -3.0e38f;
        #pragma unroll
        for (int n = 0; n < NW; ++n) {
            float sv = (mask[(tok0 + tid) * NW + n] != 0) ? -1.0e9f : sc_s[tid][n];
            v[n] = sv; m = fmaxf(m, sv);
        }
        float sum = 0.f;
        #pragma unroll
        for (int n = 0; n < NW; ++n) { float e = expf(v[n] - m); v[n] = e; sum += e; }
        float inv = 1.0f / sum;
        #pragma unroll
        for (int n = 0; n < NW; ++n) at_s[tid][n] = v[n] * inv;
    }
    __syncthreads();   // separates last weT reads from athT writes

    // ---- ATH (registers) -> athT view: smem[k*4 + tt], 16B rows ----
    #pragma unroll
    for (int tt = 0; tt < 4; ++tt) {
        float a0 = 0.f, a1 = 0.f, a2 = 0.f;
        #pragma unroll
        for (int n = 0; n < NW; ++n) {
            float w = at_s[tt][n];
            a0 = fmaf(w, th[tt * NW + n][0], a0);
            a1 = fmaf(w, th[tt * NW + n][1], a1);
            a2 = fmaf(w, th[tt * NW + n][2], a2);
        }
        smem[(0 * 256 + tid) * 4 + tt] = a0;
        smem[(1 * 256 + tid) * 4 + tt] = a1;
        smem[(2 * 256 + tid) * 4 + tt] = a2;
    }
    __syncthreads();

    // ---- GEMM2: acc[t][c] = sum_k athT[k][t] * W2[k][j] ----
    float acc[4][3];
    #pragma unroll
    for (int t = 0; t < 4; ++t) { acc[t][0] = 0.f; acc[t][1] = 0.f; acc[t][2] = 0.f; }

    #pragma unroll 4
    for (int k = 0; k < HID; ++k) {
        float4 a4 = *reinterpret_cast<const float4*>(&smem[k * 4]);
        float w0 = W2[(size_t)k * HID + tid];
        float w1 = W2[(size_t)k * HID + 256 + tid];
        float w2 = W2[(size_t)k * HID + 512 + tid];
        acc[0][0] = fmaf(a4.x, w0, acc[0][0]); acc[0][1] = fmaf(a4.x, w1, acc[0][1]); acc[0][2] = fmaf(a4.x, w2, acc[0][2]);
        acc[1][0] = fmaf(a4.y, w0, acc[1][0]); acc[1][1] = fmaf(a4.y, w1, acc[1][1]); acc[1][2] = fmaf(a4.y, w2, acc[1][2]);
        acc[2][0] = fmaf(a4.z, w0, acc[2][0]); acc[2][1] = fmaf(a4.z, w1, acc[2][1]); acc[2][2] = fmaf(a4.z, w2, acc[2][2]);
        acc[3][0] = fmaf(a4.w, w0, acc[3][0]); acc[3][1] = fmaf(a4.w, w1, acc[3][1]); acc[3][2] = fmaf(a4.w, w2, acc[3][2]);
    }

    // ---- + b2 + LO residual ----
    float v[4][3];
    {
        float bb0 = b2[tid], bb1 = b2[256 + tid], bb2 = b2[512 + tid];
        #pragma unroll
        for (int t = 0; t < 4; ++t) {
            v[t][0] = acc[t][0] + bb0 + LO[(tok0 + t) * HID + tid];
            v[t][1] = acc[t][1] + bb1 + LO[(tok0 + t) * HID + 256 + tid];
            v[t][2] = acc[t][2] + bb2 + LO[(tok0 + t) * HID + 512 + tid];
        }
    }

    // ---- LayerNorm reductions (sum, sumsq per token) ----
    #pragma unroll
    for (int t = 0; t < 4; ++t) {
        float s = v[t][0] + v[t][1] + v[t][2];
        float q = v[t][0] * v[t][0];
        q = fmaf(v[t][1], v[t][1], q);
        q = fmaf(v[t][2], v[t][2], q);
        #pragma unroll
        for (int off = 32; off; off >>= 1) { s += __shfl_xor(s, off); q += __shfl_xor(q, off); }
        if (lane == 0) { red[wave][t] = s; red[wave][4 + t] = q; }
    }
    __syncthreads();
    if (tid < 4) {
        float S = red[0][tid] + red[1][tid] + red[2][tid] + red[3][tid];
        float Q = red[0][4 + tid] + red[1][4 + tid] + red[2][4 + tid] + red[3][4 + tid];
        float mu = S * (1.0f / HID);
        float var = Q * (1.0f / HID) - mu * mu;
        mus[tid] = mu;
        rss[tid] = rsqrtf(var + 1e-12f);
    }
    __syncthreads();

    {
        float g0 = gamma[tid], g1 = gamma[256 + tid], g2 = gamma[512 + tid];
        float e0 = beta[tid],  e1 = beta[256 + tid],  e2 = beta[512 + tid];
        #pragma unroll
        for (int t = 0; t < 4; ++t) {
            float mu = mus[t], rs = rss[t];
            out[(tok0 + t) * HID + tid]       = (v[t][0] - mu) * rs * g0 + e0;
            out[(tok0 + t) * HID + 256 + tid] = (v[t][1] - mu) * rs * g1 + e1;
            out[(tok0 + t) * HID + 512 + tid] = (v[t][2] - mu) * rs * g2 + e2;
        }
    }
}

// ---------------------------------------------------------------------------
extern "C" void kernel_launch(void* const* d_in, const int* in_sizes, int n_in,
                              void* d_out, int out_size, void* d_ws, size_t ws_size,
                              hipStream_t stream)
{
    const float* LO    = (const float*)d_in[0];  // [16,512,768]
    const float* WE    = (const float*)d_in[1];  // [16,512,5,200]
    const int*   mask  = (const int*)  d_in[2];  // [16,512,5]
    const float* W1    = (const float*)d_in[3];  // [200,768]
    const float* b1    = (const float*)d_in[4];  // [768]
    const float* W2    = (const float*)d_in[5];  // [768,768]
    const float* b2    = (const float*)d_in[6];  // [768]
    const float* attnW = (const float*)d_in[7];  // [768,768]
    const float* gamma = (const float*)d_in[8];  // [768]
    const float* beta  = (const float*)d_in[9];  // [768]
    float* out = (float*)d_out;                  // [16,512,768]

    const int T = 16 * 512;  // 8192 tokens

    // workspace (floats): G [768,768]  (~2.4 MB)
    float* G = (float*)d_ws;

    gw_kernel<<<(HID / 64) * (HID / 64), 256, 0, stream>>>(attnW, W2, G);
    fused_kernel<<<T / 4, 256, 0, stream>>>(WE, W1, b1, W2, b2, LO, G, mask, gamma, beta, out);
}